// Round 1
// baseline (812.831 us; speedup 1.0000x reference)
//
#include <hip/hip_runtime.h>
#include <hip/hip_bf16.h>
#include <math.h>

#define BATCH 4
#define CIN   256   // CH_IN (value channels)
#define DQK   32    // CH_OUT (qk head dim)
#define NPIX  4096  // 64*64

typedef __attribute__((ext_vector_type(4))) float f32x4;
typedef __attribute__((ext_vector_type(8))) short bf16x8;
typedef __attribute__((ext_vector_type(4))) unsigned int u32x4;

__device__ __forceinline__ unsigned short f2bf(float f) {
  unsigned u = __builtin_bit_cast(unsigned, f);
  u += 0x7FFFu + ((u >> 16) & 1u);   // RNE
  return (unsigned short)(u >> 16);
}

// ---------------- projections ----------------
// f,g: [b][n][32] bf16 (n-major, d contiguous -> MFMA frag loads are 16B)
// grid BATCH*64 (n-tiles of 64), block 256
__global__ void proj_fg(const float* __restrict__ x,
                        const float* __restrict__ Wf, const float* __restrict__ bf,
                        const float* __restrict__ Wg, const float* __restrict__ bg,
                        unsigned short* __restrict__ F, unsigned short* __restrict__ G) {
  const int bid = blockIdx.x;
  const int b = bid >> 6;
  const int n = ((bid & 63) << 6) + (threadIdx.x & 63);
  const int rgrp = threadIdx.x >> 6;                 // 0,1 -> f rows; 2,3 -> g rows
  const float* __restrict__ W   = (rgrp < 2) ? Wf : Wg;
  const float* __restrict__ bia = (rgrp < 2) ? bf : bg;
  const int r0 = (rgrp & 1) << 4;
  float acc[16];
#pragma unroll
  for (int i = 0; i < 16; ++i) acc[i] = bia[r0 + i];
  const float* __restrict__ xp = x + (size_t)b * CIN * NPIX + n;
#pragma unroll 4
  for (int c = 0; c < CIN; c += 4) {
    const float x0 = xp[(size_t)(c + 0) * NPIX];
    const float x1 = xp[(size_t)(c + 1) * NPIX];
    const float x2 = xp[(size_t)(c + 2) * NPIX];
    const float x3 = xp[(size_t)(c + 3) * NPIX];
#pragma unroll
    for (int i = 0; i < 16; ++i) {
      const f32x4 w = *(const f32x4*)&W[(r0 + i) * CIN + c];  // wave-uniform addr
      acc[i] += w.x * x0 + w.y * x1 + w.z * x2 + w.w * x3;
    }
  }
  union { unsigned short us[16]; u32x4 v[2]; } pk;
#pragma unroll
  for (int i = 0; i < 16; ++i) pk.us[i] = f2bf(acc[i]);
  unsigned short* dst = ((rgrp < 2) ? F : G) + ((size_t)b * NPIX + n) * DQK + r0;
  ((u32x4*)dst)[0] = pk.v[0];
  ((u32x4*)dst)[1] = pk.v[1];
}

// h: [b][c][n] bf16 (c-major, n contiguous -> V^T tile staging is coalesced)
// grid BATCH*64*4 (n-tile x row-group), block 256
__global__ void proj_h(const float* __restrict__ x,
                       const float* __restrict__ Wh, const float* __restrict__ bh,
                       unsigned short* __restrict__ H) {
  const int bid = blockIdx.x;
  const int rg = bid & 3;
  const int n = (((bid >> 2) & 63) << 6) + (threadIdx.x & 63);
  const int b = bid >> 8;
  const int r0 = (rg << 6) + ((threadIdx.x >> 6) << 4);
  float acc[16];
#pragma unroll
  for (int i = 0; i < 16; ++i) acc[i] = bh[r0 + i];
  const float* __restrict__ xp = x + (size_t)b * CIN * NPIX + n;
#pragma unroll 4
  for (int c = 0; c < CIN; c += 4) {
    const float x0 = xp[(size_t)(c + 0) * NPIX];
    const float x1 = xp[(size_t)(c + 1) * NPIX];
    const float x2 = xp[(size_t)(c + 2) * NPIX];
    const float x3 = xp[(size_t)(c + 3) * NPIX];
#pragma unroll
    for (int i = 0; i < 16; ++i) {
      const f32x4 w = *(const f32x4*)&Wh[(r0 + i) * CIN + c];
      acc[i] += w.x * x0 + w.y * x1 + w.z * x2 + w.w * x3;
    }
  }
  unsigned short* dst = H + ((size_t)b * CIN + r0) * NPIX + n;
#pragma unroll
  for (int i = 0; i < 16; ++i) dst[(size_t)i * NPIX] = f2bf(acc[i]);
}

// ---------------- fused flash attention ----------------
// Q = g [b][m][32], K = f [b][n][32], V^T = h [b][c][n]
// out[b][c][m] = (1/L_m) * sum_n exp(f_n.g_m - M_m) h[c][n]
//
// grid: BATCH*64 (query tiles of 64), block 512 = 8 waves:
//   wave w: m-group (w>>2) -> 32 queries (2 MFMA col-tiles), c-group (w&3) -> 64 channels.
// Per n-tile (BN=32): S^T = K*Q^T via mfma (D[n][m]) -> per-column online softmax via
// 4-lane butterfly -> P (bf16) via per-wave LDS -> O^T += V^T*P via mfma.
// LDS rows padded to 80B (stride 20 banks -> ~2-way conflicts, free per m136).
#define BN 32
__launch_bounds__(512, 2)
__global__ void attn_kernel(const unsigned short* __restrict__ F,
                            const unsigned short* __restrict__ G,
                            const unsigned short* __restrict__ H,
                            float* __restrict__ out) {
  __shared__ unsigned short Klds[32 * 40];        // [n][32d + pad]
  __shared__ unsigned short Vlds[256 * 40];       // [c][32n + pad]
  __shared__ unsigned short Plds[8][32 * 40];     // per-wave [m][32n + pad]

  const int bid = blockIdx.x;
  const int b = bid >> 6;
  const int t = threadIdx.x;
  const int lane = t & 63;
  const int w = t >> 6;
  const int l16 = lane & 15;
  const int lhi = lane >> 4;
  const int m0 = ((bid & 63) << 6) + ((w >> 2) << 5);
  const int c0 = (w & 3) << 6;

  const f32x4 fzero = {0.f, 0.f, 0.f, 0.f};

  // Q fragments (B-operand): lane holds G[m0+mt*16+l16][lhi*8 .. +7]
  bf16x8 qf[2];
#pragma unroll
  for (int mt = 0; mt < 2; ++mt)
    qf[mt] = *(const bf16x8*)(G + ((size_t)b * NPIX + m0 + mt * 16 + l16) * DQK + lhi * 8);

  f32x4 acc[4][2];
#pragma unroll
  for (int ct = 0; ct < 4; ++ct)
#pragma unroll
    for (int mt = 0; mt < 2; ++mt) acc[ct][mt] = fzero;
  float Mr[2] = {-INFINITY, -INFINITY};
  float Lr[2] = {0.f, 0.f};

  const unsigned short* Fb = F + (size_t)b * NPIX * DQK;
  const unsigned short* Hb = H + (size_t)b * CIN * NPIX;
  unsigned short* Pw = &Plds[w][0];

  for (int n0 = 0; n0 < NPIX; n0 += BN) {
    __syncthreads();  // prev-tile K/V reads done before overwrite
    if (t < 128) {    // stage K: 32 rows x 32 bf16
      const int nr = t >> 2, sl = t & 3;
      *(u32x4*)&Klds[nr * 40 + sl * 8] = *(const u32x4*)(Fb + (size_t)(n0 + nr) * DQK + sl * 8);
    }
#pragma unroll
    for (int i = 0; i < 2; ++i) {  // stage V^T: 256 rows x 32 bf16
      const int q = t + i * 512;
      const int cr = q >> 2, sl = q & 3;
      *(u32x4*)&Vlds[cr * 40 + sl * 8] = *(const u32x4*)(Hb + (size_t)cr * NPIX + n0 + sl * 8);
    }
    __syncthreads();

    // S^T = K * Q^T : D[n-row][m-col]; lane holds rows lhi*4+v, col l16
    bf16x8 kf[2];
#pragma unroll
    for (int nts = 0; nts < 2; ++nts)
      kf[nts] = *(const bf16x8*)&Klds[(nts * 16 + l16) * 40 + lhi * 8];
    f32x4 s[2][2];
#pragma unroll
    for (int mt = 0; mt < 2; ++mt)
#pragma unroll
      for (int nts = 0; nts < 2; ++nts)
        s[mt][nts] = __builtin_amdgcn_mfma_f32_16x16x32_bf16(kf[nts], qf[mt], fzero, 0, 0, 0);

    // online softmax per query column (lanes {l16, l16+16, +32, +48} share a column)
#pragma unroll
    for (int mt = 0; mt < 2; ++mt) {
      float tmax = s[mt][0][0];
#pragma unroll
      for (int v = 1; v < 4; ++v) tmax = fmaxf(tmax, s[mt][0][v]);
#pragma unroll
      for (int v = 0; v < 4; ++v) tmax = fmaxf(tmax, s[mt][1][v]);
      tmax = fmaxf(tmax, __shfl_xor(tmax, 16, 64));
      tmax = fmaxf(tmax, __shfl_xor(tmax, 32, 64));
      const float newM = fmaxf(Mr[mt], tmax);
      const float rescale = __expf(Mr[mt] - newM);  // first tile: exp(-inf)=0
      Mr[mt] = newM;
      float p[2][4];
      float psum = 0.f;
#pragma unroll
      for (int nts = 0; nts < 2; ++nts)
#pragma unroll
        for (int v = 0; v < 4; ++v) {
          p[nts][v] = __expf(s[mt][nts][v] - newM);
          psum += p[nts][v];
        }
      psum += __shfl_xor(psum, 16, 64);
      psum += __shfl_xor(psum, 32, 64);
      Lr[mt] = Lr[mt] * rescale + psum;
#pragma unroll
      for (int ct = 0; ct < 4; ++ct) acc[ct][mt] *= rescale;
      // P[m-row][n-col]: row = mt*16+l16, cols nts*16 + lhi*4 + {0..3}
#pragma unroll
      for (int nts = 0; nts < 2; ++nts) {
        uint2 pkv;
        pkv.x = (unsigned)f2bf(p[nts][0]) | ((unsigned)f2bf(p[nts][1]) << 16);
        pkv.y = (unsigned)f2bf(p[nts][2]) | ((unsigned)f2bf(p[nts][3]) << 16);
        *(uint2*)&Pw[(mt * 16 + l16) * 40 + nts * 16 + lhi * 4] = pkv;
      }
    }
    asm volatile("" ::: "memory");  // don't reorder P reads above P writes (same-wave LDS is in-order)

    // O^T += V^T * P : A=V^T (lane: row c=l16, k=n=lhi*8+j), B=P (lane: k=n=lhi*8+j, col m=l16)
    bf16x8 pf[2];
#pragma unroll
    for (int mt = 0; mt < 2; ++mt)
      pf[mt] = *(const bf16x8*)&Pw[(mt * 16 + l16) * 40 + lhi * 8];
#pragma unroll
    for (int ct = 0; ct < 4; ++ct) {
      const bf16x8 vf = *(const bf16x8*)&Vlds[(c0 + ct * 16 + l16) * 40 + lhi * 8];
#pragma unroll
      for (int mt = 0; mt < 2; ++mt)
        acc[ct][mt] = __builtin_amdgcn_mfma_f32_16x16x32_bf16(vf, pf[mt], acc[ct][mt], 0, 0, 0);
    }
  }

  // epilogue: normalize and store; D layout: c = c0+ct*16+lhi*4+v, m = m0+mt*16+l16
#pragma unroll
  for (int mt = 0; mt < 2; ++mt) {
    const float invL = 1.f / Lr[mt];
    const int m = m0 + mt * 16 + l16;
#pragma unroll
    for (int ct = 0; ct < 4; ++ct)
#pragma unroll
      for (int v = 0; v < 4; ++v) {
        const int c = c0 + ct * 16 + lhi * 4 + v;
        out[((size_t)b * CIN + c) * NPIX + m] = acc[ct][mt][v] * invL;
      }
  }
}

extern "C" void kernel_launch(void* const* d_in, const int* in_sizes, int n_in,
                              void* d_out, int out_size, void* d_ws, size_t ws_size,
                              hipStream_t stream) {
  (void)in_sizes; (void)n_in; (void)out_size; (void)ws_size;
  const float* x  = (const float*)d_in[0];
  const float* Wf = (const float*)d_in[1];
  const float* bf = (const float*)d_in[2];
  const float* Wg = (const float*)d_in[3];
  const float* bg = (const float*)d_in[4];
  const float* Wh = (const float*)d_in[5];
  const float* bh = (const float*)d_in[6];
  float* out = (float*)d_out;

  // workspace carve-out (bf16): F 1MB | G 1MB | H 8MB  (total 10.5MB)
  unsigned short* Fw = (unsigned short*)d_ws;
  unsigned short* Gw = Fw + (size_t)BATCH * NPIX * DQK;
  unsigned short* Hw = Gw + (size_t)BATCH * NPIX * DQK;

  hipLaunchKernelGGL(proj_fg, dim3(BATCH * 64), dim3(256), 0, stream, x, Wf, bf, Wg, bg, Fw, Gw);
  hipLaunchKernelGGL(proj_h,  dim3(BATCH * 64 * 4), dim3(256), 0, stream, x, Wh, bh, Hw);
  hipLaunchKernelGGL(attn_kernel, dim3(BATCH * 64), dim3(512), 0, stream, Fw, Gw, Hw, out);
}

// Round 2
// 210.286 us; speedup vs baseline: 3.8654x; 3.8654x over previous
//
#include <hip/hip_runtime.h>
#include <hip/hip_bf16.h>
#include <math.h>

#define BATCH 4
#define CIN   256   // CH_IN (value channels)
#define DQK   32    // CH_OUT (qk head dim)
#define NPIX  4096  // 64*64
#define MTOT  320   // 256 (Wh) + 32 (Wf) + 32 (Wg)

typedef __attribute__((ext_vector_type(4))) float f32x4;
typedef __attribute__((ext_vector_type(8))) short bf16x8;
typedef __attribute__((ext_vector_type(4))) unsigned int u32x4;

__device__ __forceinline__ unsigned short f2bf(float f) {
  unsigned u = __builtin_bit_cast(unsigned, f);
  u += 0x7FFFu + ((u >> 16) & 1u);   // RNE
  return (unsigned short)(u >> 16);
}

// ---------------- W convert: concat [320][256] f32 -> bf16, bias concat f32[320] ----------------
// grid 320 (row per block), block 256
__global__ void wcvt(const float* __restrict__ Wh, const float* __restrict__ Wf,
                     const float* __restrict__ Wg,
                     const float* __restrict__ bh, const float* __restrict__ bf,
                     const float* __restrict__ bg,
                     unsigned short* __restrict__ Wb, float* __restrict__ bcat) {
  const int r = blockIdx.x;
  const int c = threadIdx.x;
  const float* src = (r < 256) ? &Wh[r * CIN] : (r < 288) ? &Wf[(r - 256) * CIN] : &Wg[(r - 288) * CIN];
  Wb[r * CIN + c] = f2bf(src[c]);
  if (c == 0)
    bcat[r] = (r < 256) ? bh[r] : (r < 288) ? bf[r - 256] : bg[r - 288];
}

// ---------------- fused projection GEMM ----------------
// D[320][4096] = Wcat[320][256] x X[256][4096] + bias, per batch.
// grid: 4b * 64 pixel-tiles of 64. block 512 = 8 waves, split 4M x 2N.
// X tile staged ONCE (full K=256) into LDS transposed [n][k] bf16 -> x read from HBM exactly once.
// Rows 0-255 -> H [b][c][n]; rows 256-287 -> F [b][n][32]; 288-319 -> G [b][n][32].
#define XPAD 4          // row stride 260 elems = 520 B (130 banks) -> b128 reads at min aliasing
__launch_bounds__(512, 1)
__global__ void proj_all(const float* __restrict__ x, const unsigned short* __restrict__ Wb,
                         const float* __restrict__ bcat,
                         unsigned short* __restrict__ F, unsigned short* __restrict__ G,
                         unsigned short* __restrict__ H) {
  __shared__ unsigned short Xs[64 * (CIN + XPAD)];   // [n][256k + pad] = 33.3 KB

  const int bid = blockIdx.x;
  const int b = bid >> 6;
  const int n0 = (bid & 63) << 6;
  const int t = threadIdx.x;
  const int lane = t & 63;
  const int w = t >> 6;

  // ---- stage + transpose: x[b][k][n0+lane] f32 -> Xs[lane][k] bf16 (pairs packed to b32) ----
  const float* __restrict__ xb = x + (size_t)b * CIN * NPIX + n0;
#pragma unroll
  for (int p = 0; p < 16; ++p) {
    const int k = p * 16 + w * 2;                       // even; each wave covers k = 2w + 16p
    const float a0 = xb[(size_t)k * NPIX + lane];       // 256B coalesced
    const float a1 = xb[(size_t)(k + 1) * NPIX + lane];
    const unsigned pk = (unsigned)f2bf(a0) | ((unsigned)f2bf(a1) << 16);
    *(unsigned*)((char*)Xs + lane * (CIN + XPAD) * 2 + k * 2) = pk;
  }
  __syncthreads();

  const int l16 = lane & 15, lhi = lane >> 4;
  const int wm = w >> 1;            // 0..3 -> 80 rows each
  const int wn = w & 1;             // 0..1 -> 32 px each

  const f32x4 fzero = {0.f, 0.f, 0.f, 0.f};
  f32x4 acc[5][2];
#pragma unroll
  for (int i = 0; i < 5; ++i)
#pragma unroll
    for (int j = 0; j < 2; ++j) acc[i][j] = fzero;

  // ---- K loop: 8 steps of 32; A-frags direct from global bf16 W (L1/L2-resident) ----
#pragma unroll
  for (int ks = 0; ks < 8; ++ks) {
    bf16x8 bx[2];
#pragma unroll
    for (int j = 0; j < 2; ++j)
      bx[j] = *(const bf16x8*)&Xs[(wn * 32 + j * 16 + l16) * (CIN + XPAD) + ks * 32 + lhi * 8];
#pragma unroll
    for (int i = 0; i < 5; ++i) {
      const bf16x8 aw = *(const bf16x8*)(Wb + (size_t)(wm * 80 + i * 16 + l16) * CIN + ks * 32 + lhi * 8);
#pragma unroll
      for (int j = 0; j < 2; ++j)
        acc[i][j] = __builtin_amdgcn_mfma_f32_16x16x32_bf16(aw, bx[j], acc[i][j], 0, 0, 0);
    }
  }

  // ---- epilogue: + bias, store. D frag: col n = l16, rows m = m0 + lhi*4 + v ----
#pragma unroll
  for (int i = 0; i < 5; ++i) {
    const int MT = wm * 5 + i;
    const int m0 = MT * 16;
    const f32x4 bias = *(const f32x4*)&bcat[m0 + lhi * 4];
#pragma unroll
    for (int j = 0; j < 2; ++j) {
      const int n = n0 + wn * 32 + j * 16 + l16;
      f32x4 v = acc[i][j];
      v.x += bias.x; v.y += bias.y; v.z += bias.z; v.w += bias.w;
      if (MT < 16) {          // H rows c = m0+lhi*4+r, col n
        const int c0 = m0 + lhi * 4;
        unsigned short* dst = H + ((size_t)b * CIN + c0) * NPIX + n;
        dst[0 * NPIX] = f2bf(v.x);
        dst[1 * NPIX] = f2bf(v.y);
        dst[2 * NPIX] = f2bf(v.z);
        dst[3 * NPIX] = f2bf(v.w);
      } else {                // F/G packed [n][32]: 8B per lane
        unsigned short* dst = (MT < 18) ? F : G;
        const int d0 = ((MT - 16) & 1) * 16 + lhi * 4;
        uint2 pk;
        pk.x = (unsigned)f2bf(v.x) | ((unsigned)f2bf(v.y) << 16);
        pk.y = (unsigned)f2bf(v.z) | ((unsigned)f2bf(v.w) << 16);
        *(uint2*)(dst + ((size_t)b * NPIX + n) * DQK + d0) = pk;
      }
    }
  }
}

// ---------------- fused flash attention (unchanged from round 1) ----------------
// Q = g [b][m][32], K = f [b][n][32], V^T = h [b][c][n]
#define BN 32
__launch_bounds__(512, 2)
__global__ void attn_kernel(const unsigned short* __restrict__ F,
                            const unsigned short* __restrict__ G,
                            const unsigned short* __restrict__ H,
                            float* __restrict__ out) {
  __shared__ unsigned short Klds[32 * 40];        // [n][32d + pad]
  __shared__ unsigned short Vlds[256 * 40];       // [c][32n + pad]
  __shared__ unsigned short Plds[8][32 * 40];     // per-wave [m][32n + pad]

  const int bid = blockIdx.x;
  const int b = bid >> 6;
  const int t = threadIdx.x;
  const int lane = t & 63;
  const int w = t >> 6;
  const int l16 = lane & 15;
  const int lhi = lane >> 4;
  const int m0 = ((bid & 63) << 6) + ((w >> 2) << 5);
  const int c0 = (w & 3) << 6;

  const f32x4 fzero = {0.f, 0.f, 0.f, 0.f};

  bf16x8 qf[2];
#pragma unroll
  for (int mt = 0; mt < 2; ++mt)
    qf[mt] = *(const bf16x8*)(G + ((size_t)b * NPIX + m0 + mt * 16 + l16) * DQK + lhi * 8);

  f32x4 acc[4][2];
#pragma unroll
  for (int ct = 0; ct < 4; ++ct)
#pragma unroll
    for (int mt = 0; mt < 2; ++mt) acc[ct][mt] = fzero;
  float Mr[2] = {-INFINITY, -INFINITY};
  float Lr[2] = {0.f, 0.f};

  const unsigned short* Fb = F + (size_t)b * NPIX * DQK;
  const unsigned short* Hb = H + (size_t)b * CIN * NPIX;
  unsigned short* Pw = &Plds[w][0];

  for (int n0 = 0; n0 < NPIX; n0 += BN) {
    __syncthreads();
    if (t < 128) {
      const int nr = t >> 2, sl = t & 3;
      *(u32x4*)&Klds[nr * 40 + sl * 8] = *(const u32x4*)(Fb + (size_t)(n0 + nr) * DQK + sl * 8);
    }
#pragma unroll
    for (int i = 0; i < 2; ++i) {
      const int q = t + i * 512;
      const int cr = q >> 2, sl = q & 3;
      *(u32x4*)&Vlds[cr * 40 + sl * 8] = *(const u32x4*)(Hb + (size_t)cr * NPIX + n0 + sl * 8);
    }
    __syncthreads();

    bf16x8 kf[2];
#pragma unroll
    for (int nts = 0; nts < 2; ++nts)
      kf[nts] = *(const bf16x8*)&Klds[(nts * 16 + l16) * 40 + lhi * 8];
    f32x4 s[2][2];
#pragma unroll
    for (int mt = 0; mt < 2; ++mt)
#pragma unroll
      for (int nts = 0; nts < 2; ++nts)
        s[mt][nts] = __builtin_amdgcn_mfma_f32_16x16x32_bf16(kf[nts], qf[mt], fzero, 0, 0, 0);

#pragma unroll
    for (int mt = 0; mt < 2; ++mt) {
      float tmax = s[mt][0][0];
#pragma unroll
      for (int v = 1; v < 4; ++v) tmax = fmaxf(tmax, s[mt][0][v]);
#pragma unroll
      for (int v = 0; v < 4; ++v) tmax = fmaxf(tmax, s[mt][1][v]);
      tmax = fmaxf(tmax, __shfl_xor(tmax, 16, 64));
      tmax = fmaxf(tmax, __shfl_xor(tmax, 32, 64));
      const float newM = fmaxf(Mr[mt], tmax);
      const float rescale = __expf(Mr[mt] - newM);
      Mr[mt] = newM;
      float p[2][4];
      float psum = 0.f;
#pragma unroll
      for (int nts = 0; nts < 2; ++nts)
#pragma unroll
        for (int v = 0; v < 4; ++v) {
          p[nts][v] = __expf(s[mt][nts][v] - newM);
          psum += p[nts][v];
        }
      psum += __shfl_xor(psum, 16, 64);
      psum += __shfl_xor(psum, 32, 64);
      Lr[mt] = Lr[mt] * rescale + psum;
#pragma unroll
      for (int ct = 0; ct < 4; ++ct) acc[ct][mt] *= rescale;
#pragma unroll
      for (int nts = 0; nts < 2; ++nts) {
        uint2 pkv;
        pkv.x = (unsigned)f2bf(p[nts][0]) | ((unsigned)f2bf(p[nts][1]) << 16);
        pkv.y = (unsigned)f2bf(p[nts][2]) | ((unsigned)f2bf(p[nts][3]) << 16);
        *(uint2*)&Pw[(mt * 16 + l16) * 40 + nts * 16 + lhi * 4] = pkv;
      }
    }
    asm volatile("" ::: "memory");

    bf16x8 pf[2];
#pragma unroll
    for (int mt = 0; mt < 2; ++mt)
      pf[mt] = *(const bf16x8*)&Pw[(mt * 16 + l16) * 40 + lhi * 8];
#pragma unroll
    for (int ct = 0; ct < 4; ++ct) {
      const bf16x8 vf = *(const bf16x8*)&Vlds[(c0 + ct * 16 + l16) * 40 + lhi * 8];
#pragma unroll
      for (int mt = 0; mt < 2; ++mt)
        acc[ct][mt] = __builtin_amdgcn_mfma_f32_16x16x32_bf16(vf, pf[mt], acc[ct][mt], 0, 0, 0);
    }
  }

#pragma unroll
  for (int mt = 0; mt < 2; ++mt) {
    const float invL = 1.f / Lr[mt];
    const int m = m0 + mt * 16 + l16;
#pragma unroll
    for (int ct = 0; ct < 4; ++ct)
#pragma unroll
      for (int v = 0; v < 4; ++v) {
        const int c = c0 + ct * 16 + lhi * 4 + v;
        out[((size_t)b * CIN + c) * NPIX + m] = acc[ct][mt][v] * invL;
      }
  }
}

extern "C" void kernel_launch(void* const* d_in, const int* in_sizes, int n_in,
                              void* d_out, int out_size, void* d_ws, size_t ws_size,
                              hipStream_t stream) {
  (void)in_sizes; (void)n_in; (void)out_size; (void)ws_size;
  const float* x  = (const float*)d_in[0];
  const float* Wf = (const float*)d_in[1];
  const float* bf = (const float*)d_in[2];
  const float* Wg = (const float*)d_in[3];
  const float* bg = (const float*)d_in[4];
  const float* Wh = (const float*)d_in[5];
  const float* bh = (const float*)d_in[6];
  float* out = (float*)d_out;

  // workspace carve-out: F 1MB | G 1MB | H 8.4MB | Wb 160KB | bcat 1.25KB
  unsigned short* Fw = (unsigned short*)d_ws;
  unsigned short* Gw = Fw + (size_t)BATCH * NPIX * DQK;
  unsigned short* Hw = Gw + (size_t)BATCH * NPIX * DQK;
  unsigned short* Wb = Hw + (size_t)BATCH * CIN * NPIX;
  float* bcat = (float*)(Wb + (size_t)MTOT * CIN);

  hipLaunchKernelGGL(wcvt, dim3(MTOT), dim3(256), 0, stream, Wh, Wf, Wg, bh, bf, bg, Wb, bcat);
  hipLaunchKernelGGL(proj_all, dim3(BATCH * 64), dim3(512), 0, stream, x, Wb, bcat, Fw, Gw, Hw);
  hipLaunchKernelGGL(attn_kernel, dim3(BATCH * 64), dim3(512), 0, stream, Fw, Gw, Hw, out);
}

// Round 3
// 88.115 us; speedup vs baseline: 9.2247x; 2.3865x over previous
//
#include <hip/hip_runtime.h>
#include <hip/hip_bf16.h>
#include <math.h>

#define BATCH 4
#define CIN   256
#define DQK   32
#define NPIX  4096
#define MTOT  320

typedef __attribute__((ext_vector_type(4))) float f32x4;
typedef __attribute__((ext_vector_type(8))) short bf16x8;
typedef __attribute__((ext_vector_type(4))) unsigned int u32x4;

__device__ __forceinline__ unsigned short f2bf(float f) {
  unsigned u = __builtin_bit_cast(unsigned, f);
  u += 0x7FFFu + ((u >> 16) & 1u);   // RNE
  return (unsigned short)(u >> 16);
}
__device__ __forceinline__ unsigned pk2(float a, float b) {
  return (unsigned)f2bf(a) | ((unsigned)f2bf(b) << 16);
}
__device__ __forceinline__ void barrier_lds() {   // barrier WITHOUT vmcnt drain
  asm volatile("s_waitcnt lgkmcnt(0)" ::: "memory");
  __builtin_amdgcn_s_barrier();
  asm volatile("" ::: "memory");
}

// ---------------- W convert ----------------
__global__ void wcvt(const float* __restrict__ Wh, const float* __restrict__ Wf,
                     const float* __restrict__ Wg,
                     const float* __restrict__ bh, const float* __restrict__ bf,
                     const float* __restrict__ bg,
                     unsigned short* __restrict__ Wb, float* __restrict__ bcat) {
  const int r = blockIdx.x;
  const int c = threadIdx.x;
  const float* src = (r < 256) ? &Wh[r * CIN] : (r < 288) ? &Wf[(r - 256) * CIN] : &Wg[(r - 288) * CIN];
  Wb[r * CIN + c] = f2bf(src[c]);
  if (c == 0)
    bcat[r] = (r < 256) ? bh[r] : (r < 288) ? bf[r - 256] : bg[r - 288];
}

// ---------------- fused projection GEMM (unchanged from round 2) ----------------
#define XPAD 4
__launch_bounds__(512, 1)
__global__ void proj_all(const float* __restrict__ x, const unsigned short* __restrict__ Wb,
                         const float* __restrict__ bcat,
                         unsigned short* __restrict__ F, unsigned short* __restrict__ G,
                         unsigned short* __restrict__ H) {
  __shared__ unsigned short Xs[64 * (CIN + XPAD)];

  const int bid = blockIdx.x;
  const int b = bid >> 6;
  const int n0 = (bid & 63) << 6;
  const int t = threadIdx.x;
  const int lane = t & 63;
  const int w = t >> 6;

  const float* __restrict__ xb = x + (size_t)b * CIN * NPIX + n0;
#pragma unroll
  for (int p = 0; p < 16; ++p) {
    const int k = p * 16 + w * 2;
    const float a0 = xb[(size_t)k * NPIX + lane];
    const float a1 = xb[(size_t)(k + 1) * NPIX + lane];
    const unsigned pk = (unsigned)f2bf(a0) | ((unsigned)f2bf(a1) << 16);
    *(unsigned*)((char*)Xs + lane * (CIN + XPAD) * 2 + k * 2) = pk;
  }
  __syncthreads();

  const int l16 = lane & 15, lhi = lane >> 4;
  const int wm = w >> 1;
  const int wn = w & 1;

  const f32x4 fzero = {0.f, 0.f, 0.f, 0.f};
  f32x4 acc[5][2];
#pragma unroll
  for (int i = 0; i < 5; ++i)
#pragma unroll
    for (int j = 0; j < 2; ++j) acc[i][j] = fzero;

#pragma unroll
  for (int ks = 0; ks < 8; ++ks) {
    bf16x8 bx[2];
#pragma unroll
    for (int j = 0; j < 2; ++j)
      bx[j] = *(const bf16x8*)&Xs[(wn * 32 + j * 16 + l16) * (CIN + XPAD) + ks * 32 + lhi * 8];
#pragma unroll
    for (int i = 0; i < 5; ++i) {
      const bf16x8 aw = *(const bf16x8*)(Wb + (size_t)(wm * 80 + i * 16 + l16) * CIN + ks * 32 + lhi * 8);
#pragma unroll
      for (int j = 0; j < 2; ++j)
        acc[i][j] = __builtin_amdgcn_mfma_f32_16x16x32_bf16(aw, bx[j], acc[i][j], 0, 0, 0);
    }
  }

#pragma unroll
  for (int i = 0; i < 5; ++i) {
    const int MT = wm * 5 + i;
    const int m0 = MT * 16;
    const f32x4 bias = *(const f32x4*)&bcat[m0 + lhi * 4];
#pragma unroll
    for (int j = 0; j < 2; ++j) {
      const int n = n0 + wn * 32 + j * 16 + l16;
      f32x4 v = acc[i][j];
      v.x += bias.x; v.y += bias.y; v.z += bias.z; v.w += bias.w;
      if (MT < 16) {
        const int c0 = m0 + lhi * 4;
        unsigned short* dst = H + ((size_t)b * CIN + c0) * NPIX + n;
        dst[0 * NPIX] = f2bf(v.x);
        dst[1 * NPIX] = f2bf(v.y);
        dst[2 * NPIX] = f2bf(v.z);
        dst[3 * NPIX] = f2bf(v.w);
      } else {
        unsigned short* dst = (MT < 18) ? F : G;
        const int d0 = ((MT - 16) & 1) * 16 + lhi * 4;
        uint2 pk;
        pk.x = (unsigned)f2bf(v.x) | ((unsigned)f2bf(v.y) << 16);
        pk.y = (unsigned)f2bf(v.z) | ((unsigned)f2bf(v.w) << 16);
        *(uint2*)(dst + ((size_t)b * NPIX + n) * DQK + d0) = pk;
      }
    }
  }
}

// ---------------- key-split flash attention (M=0, dedup'd softmax) ----------------
// grid: 4b x 32 q-tiles(128q) x 2 key-splits(2048 keys). block 512 = 8 waves:
//   wave = (mg in {0,1}: 64 queries, mt=4) x (cs in {0..3}: 64 channels, ct=4; also owns nts=cs of S).
// Per BN=64 tile: QK (nts-split, zero redundancy) -> p=exp(s) (M=0; data-bounded scores)
// -> P shared per m-group in LDS -> PV with 4x4 frag reuse. K/V double-buffered LDS,
// 2-tile register prefetch, lgkmcnt-only barriers (global loads stay in flight).
// Outputs unnormalized A (bf16) + L partials; combine pass normalizes.
#define QT   128
#define BNK  64
#define KEYS 2048
#define NTILE (KEYS / BNK)   // 32

__launch_bounds__(512, 2)
__global__ void attn_split(const unsigned short* __restrict__ F,
                           const unsigned short* __restrict__ G,
                           const unsigned short* __restrict__ H,
                           unsigned short* __restrict__ Ap, float* __restrict__ Lp) {
  __shared__ unsigned short Kl[2][64][36];    // [buf][n][32d + pad]
  __shared__ unsigned short Vl[2][256][72];   // [buf][c][64n + pad]
  __shared__ unsigned short Pl[2][64][72];    // [m-group][q][64n + pad]

  const int bid = blockIdx.x;                 // ((b*32 + qt)*2 + split)
  const int split = bid & 1;
  const int qt = (bid >> 1) & 31;
  const int b = bid >> 6;
  const int t = threadIdx.x;
  const int lane = t & 63, w = t >> 6;
  const int l16 = lane & 15, lhi = lane >> 4;
  const int mg = w >> 2, cs = w & 3;

  const unsigned short* Fb = F + (size_t)b * NPIX * DQK;
  const unsigned short* Gb = G + (size_t)b * NPIX * DQK;
  const unsigned short* Hb = H + (size_t)b * CIN * NPIX;
  const int nb0 = split * KEYS;
  const int q0 = qt * QT + mg * 64;

  const f32x4 fzero = {0.f, 0.f, 0.f, 0.f};

  // Q fragments (B-operand): col m = l16, k = lhi*8..+7
  bf16x8 qf[4];
#pragma unroll
  for (int mt = 0; mt < 4; ++mt)
    qf[mt] = *(const bf16x8*)(Gb + (size_t)(q0 + mt * 16 + l16) * DQK + lhi * 8);

  f32x4 acc[4][4];
#pragma unroll
  for (int ct = 0; ct < 4; ++ct)
#pragma unroll
    for (int mt = 0; mt < 4; ++mt) acc[ct][mt] = fzero;
  float Lacc[4] = {0.f, 0.f, 0.f, 0.f};

  // staging thread mapping (coalesced global, <=2-way LDS write conflicts)
  const int vrow = t >> 3, vslot = t & 7;   // V: 4 chunks of rows i*64+vrow
  const int krow = t >> 2, kslot = t & 3;   // K: threads < 256

  u32x4 vr0[4], vr1[4], kr0, kr1;

#define STAGE_LOAD(VR, KR, TILE_) do {                                                   \
    const int nb_ = nb0 + (TILE_) * BNK;                                                 \
    _Pragma("unroll")                                                                    \
    for (int i_ = 0; i_ < 4; ++i_)                                                       \
      VR[i_] = *(const u32x4*)(Hb + (size_t)(i_ * 64 + vrow) * NPIX + nb_ + vslot * 8);  \
    if (t < 256) KR = *(const u32x4*)(Fb + (size_t)(nb_ + krow) * DQK + kslot * 8);      \
  } while (0)

#define STAGE_STORE(VR, KR, BUF) do {                                                    \
    _Pragma("unroll")                                                                    \
    for (int i_ = 0; i_ < 4; ++i_)                                                       \
      *(u32x4*)&Vl[BUF][i_ * 64 + vrow][vslot * 8] = VR[i_];                             \
    if (t < 256) *(u32x4*)&Kl[BUF][krow][kslot * 8] = KR;                                \
  } while (0)

#define COMPUTE(BUF) do {                                                                \
    const bf16x8 kf = *(const bf16x8*)&Kl[BUF][cs * 16 + l16][lhi * 8];                  \
    f32x4 s_[4];                                                                         \
    _Pragma("unroll")                                                                    \
    for (int mt = 0; mt < 4; ++mt)                                                       \
      s_[mt] = __builtin_amdgcn_mfma_f32_16x16x32_bf16(kf, qf[mt], fzero, 0, 0, 0);      \
    _Pragma("unroll")                                                                    \
    for (int mt = 0; mt < 4; ++mt) {                                                     \
      const float p0 = __expf(s_[mt][0]), p1 = __expf(s_[mt][1]);                        \
      const float p2 = __expf(s_[mt][2]), p3 = __expf(s_[mt][3]);                        \
      Lacc[mt] += (p0 + p1) + (p2 + p3);                                                 \
      uint2 pk; pk.x = pk2(p0, p1); pk.y = pk2(p2, p3);                                  \
      *(uint2*)&Pl[mg][mt * 16 + l16][cs * 16 + lhi * 4] = pk;                           \
    }                                                                                    \
    barrier_lds();                                                                       \
    _Pragma("unroll")                                                                    \
    for (int kk = 0; kk < 2; ++kk) {                                                     \
      bf16x8 pf[4];                                                                      \
      _Pragma("unroll")                                                                  \
      for (int mt = 0; mt < 4; ++mt)                                                     \
        pf[mt] = *(const bf16x8*)&Pl[mg][mt * 16 + l16][kk * 32 + lhi * 8];              \
      _Pragma("unroll")                                                                  \
      for (int ct = 0; ct < 4; ++ct) {                                                   \
        const bf16x8 vf = *(const bf16x8*)&Vl[BUF][cs * 64 + ct * 16 + l16][kk * 32 + lhi * 8]; \
        _Pragma("unroll")                                                                \
        for (int mt = 0; mt < 4; ++mt)                                                   \
          acc[ct][mt] = __builtin_amdgcn_mfma_f32_16x16x32_bf16(vf, pf[mt], acc[ct][mt], 0, 0, 0); \
      }                                                                                  \
    }                                                                                    \
    barrier_lds();                                                                       \
  } while (0)

  // prologue
  STAGE_LOAD(vr0, kr0, 0);
  STAGE_STORE(vr0, kr0, 0);
  STAGE_LOAD(vr1, kr1, 1);
  barrier_lds();

  for (int tt = 0; tt < NTILE; tt += 2) {
    // parity 0
    if (tt + 1 < NTILE) STAGE_STORE(vr1, kr1, 1);
    if (tt + 2 < NTILE) STAGE_LOAD(vr0, kr0, tt + 2);
    COMPUTE(0);
    // parity 1
    if (tt + 2 < NTILE) STAGE_STORE(vr0, kr0, 0);
    if (tt + 3 < NTILE) STAGE_LOAD(vr1, kr1, tt + 3);
    COMPUTE(1);
  }

  // epilogue: L partials (summed over lhi), unnormalized A in bf16
#pragma unroll
  for (int mt = 0; mt < 4; ++mt) {
    float L = Lacc[mt];
    L += __shfl_xor(L, 16, 64);
    L += __shfl_xor(L, 32, 64);
    if (lhi == 0)
      Lp[((size_t)split * 4 + cs) * (4 * NPIX) + (size_t)b * NPIX + q0 + mt * 16 + l16] = L;
  }
#pragma unroll
  for (int ct = 0; ct < 4; ++ct)
#pragma unroll
    for (int mt = 0; mt < 4; ++mt) {
      const int c = cs * 64 + ct * 16 + lhi * 4;
      const int q = q0 + mt * 16 + l16;
      unsigned short* dst = Ap + (((size_t)split * 4 + b) * CIN + c) * NPIX + q;
#pragma unroll
      for (int v = 0; v < 4; ++v) dst[(size_t)v * NPIX] = f2bf(acc[ct][mt][v]);
    }
#undef STAGE_LOAD
#undef STAGE_STORE
#undef COMPUTE
}

// sum the 8 L partials -> 1/L
__global__ void combineL(const float* __restrict__ Lp, float* __restrict__ Linv) {
  const int idx = blockIdx.x * 256 + threadIdx.x;   // b*NPIX + q, 16384 total
  float s = 0.f;
#pragma unroll
  for (int i = 0; i < 8; ++i) s += Lp[(size_t)i * (4 * NPIX) + idx];
  Linv[idx] = 1.f / s;
}

// out[b][c][q] = (A0 + A1) * Linv[b][q]
__global__ void combine(const unsigned short* __restrict__ Ap, const float* __restrict__ Linv,
                        float* __restrict__ out) {
  const size_t base = ((size_t)blockIdx.x * 256 + threadIdx.x) * 8;
  const int b = (int)(base / ((size_t)CIN * NPIX));
  const int q = (int)(base % NPIX);
  const u32x4 a0 = *(const u32x4*)(Ap + base);
  const u32x4 a1 = *(const u32x4*)(Ap + (size_t)4 * CIN * NPIX + base);
  const float* lv = &Linv[(size_t)b * NPIX + q];
  float r[8];
#pragma unroll
  for (int i = 0; i < 4; ++i) {
    const float x0 = __builtin_bit_cast(float, (a0[i] & 0xFFFFu) << 16) +
                     __builtin_bit_cast(float, (a1[i] & 0xFFFFu) << 16);
    const float x1 = __builtin_bit_cast(float, (a0[i] & 0xFFFF0000u)) +
                     __builtin_bit_cast(float, (a1[i] & 0xFFFF0000u));
    r[2 * i] = x0 * lv[2 * i];
    r[2 * i + 1] = x1 * lv[2 * i + 1];
  }
  *(f32x4*)&out[base] = *(f32x4*)&r[0];
  *(f32x4*)&out[base + 4] = *(f32x4*)&r[4];
}

// ---------------- round-2 flash attention (fallback if ws too small) ----------------
#define BN 32
__launch_bounds__(512, 2)
__global__ void attn_kernel(const unsigned short* __restrict__ F,
                            const unsigned short* __restrict__ G,
                            const unsigned short* __restrict__ H,
                            float* __restrict__ out) {
  __shared__ unsigned short Klds[32 * 40];
  __shared__ unsigned short Vlds[256 * 40];
  __shared__ unsigned short Plds[8][32 * 40];

  const int bid = blockIdx.x;
  const int b = bid >> 6;
  const int t = threadIdx.x;
  const int lane = t & 63;
  const int w = t >> 6;
  const int l16 = lane & 15;
  const int lhi = lane >> 4;
  const int m0 = ((bid & 63) << 6) + ((w >> 2) << 5);
  const int c0 = (w & 3) << 6;

  const f32x4 fzero = {0.f, 0.f, 0.f, 0.f};

  bf16x8 qf[2];
#pragma unroll
  for (int mt = 0; mt < 2; ++mt)
    qf[mt] = *(const bf16x8*)(G + ((size_t)b * NPIX + m0 + mt * 16 + l16) * DQK + lhi * 8);

  f32x4 acc[4][2];
#pragma unroll
  for (int ct = 0; ct < 4; ++ct)
#pragma unroll
    for (int mt = 0; mt < 2; ++mt) acc[ct][mt] = fzero;
  float Mr[2] = {-INFINITY, -INFINITY};
  float Lr[2] = {0.f, 0.f};

  const unsigned short* Fb = F + (size_t)b * NPIX * DQK;
  const unsigned short* Hb = H + (size_t)b * CIN * NPIX;
  unsigned short* Pw = &Plds[w][0];

  for (int n0 = 0; n0 < NPIX; n0 += BN) {
    __syncthreads();
    if (t < 128) {
      const int nr = t >> 2, sl = t & 3;
      *(u32x4*)&Klds[nr * 40 + sl * 8] = *(const u32x4*)(Fb + (size_t)(n0 + nr) * DQK + sl * 8);
    }
#pragma unroll
    for (int i = 0; i < 2; ++i) {
      const int q = t + i * 512;
      const int cr = q >> 2, sl = q & 3;
      *(u32x4*)&Vlds[cr * 40 + sl * 8] = *(const u32x4*)(Hb + (size_t)cr * NPIX + n0 + sl * 8);
    }
    __syncthreads();

    bf16x8 kf[2];
#pragma unroll
    for (int nts = 0; nts < 2; ++nts)
      kf[nts] = *(const bf16x8*)&Klds[(nts * 16 + l16) * 40 + lhi * 8];
    f32x4 s[2][2];
#pragma unroll
    for (int mt = 0; mt < 2; ++mt)
#pragma unroll
      for (int nts = 0; nts < 2; ++nts)
        s[mt][nts] = __builtin_amdgcn_mfma_f32_16x16x32_bf16(kf[nts], qf[mt], fzero, 0, 0, 0);

#pragma unroll
    for (int mt = 0; mt < 2; ++mt) {
      float tmax = s[mt][0][0];
#pragma unroll
      for (int v = 1; v < 4; ++v) tmax = fmaxf(tmax, s[mt][0][v]);
#pragma unroll
      for (int v = 0; v < 4; ++v) tmax = fmaxf(tmax, s[mt][1][v]);
      tmax = fmaxf(tmax, __shfl_xor(tmax, 16, 64));
      tmax = fmaxf(tmax, __shfl_xor(tmax, 32, 64));
      const float newM = fmaxf(Mr[mt], tmax);
      const float rescale = __expf(Mr[mt] - newM);
      Mr[mt] = newM;
      float p[2][4];
      float psum = 0.f;
#pragma unroll
      for (int nts = 0; nts < 2; ++nts)
#pragma unroll
        for (int v = 0; v < 4; ++v) {
          p[nts][v] = __expf(s[mt][nts][v] - newM);
          psum += p[nts][v];
        }
      psum += __shfl_xor(psum, 16, 64);
      psum += __shfl_xor(psum, 32, 64);
      Lr[mt] = Lr[mt] * rescale + psum;
#pragma unroll
      for (int ct = 0; ct < 4; ++ct) acc[ct][mt] *= rescale;
#pragma unroll
      for (int nts = 0; nts < 2; ++nts) {
        uint2 pkv;
        pkv.x = (unsigned)f2bf(p[nts][0]) | ((unsigned)f2bf(p[nts][1]) << 16);
        pkv.y = (unsigned)f2bf(p[nts][2]) | ((unsigned)f2bf(p[nts][3]) << 16);
        *(uint2*)&Pw[(mt * 16 + l16) * 40 + nts * 16 + lhi * 4] = pkv;
      }
    }
    asm volatile("" ::: "memory");

    bf16x8 pf[2];
#pragma unroll
    for (int mt = 0; mt < 2; ++mt)
      pf[mt] = *(const bf16x8*)&Pw[(mt * 16 + l16) * 40 + lhi * 8];
#pragma unroll
    for (int ct = 0; ct < 4; ++ct) {
      const bf16x8 vf = *(const bf16x8*)&Vlds[(c0 + ct * 16 + l16) * 40 + lhi * 8];
#pragma unroll
      for (int mt = 0; mt < 2; ++mt)
        acc[ct][mt] = __builtin_amdgcn_mfma_f32_16x16x32_bf16(vf, pf[mt], acc[ct][mt], 0, 0, 0);
    }
  }

#pragma unroll
  for (int mt = 0; mt < 2; ++mt) {
    const float invL = 1.f / Lr[mt];
    const int m = m0 + mt * 16 + l16;
#pragma unroll
    for (int ct = 0; ct < 4; ++ct)
#pragma unroll
      for (int v = 0; v < 4; ++v) {
        const int c = c0 + ct * 16 + lhi * 4 + v;
        out[((size_t)b * CIN + c) * NPIX + m] = acc[ct][mt][v] * invL;
      }
  }
}

extern "C" void kernel_launch(void* const* d_in, const int* in_sizes, int n_in,
                              void* d_out, int out_size, void* d_ws, size_t ws_size,
                              hipStream_t stream) {
  (void)in_sizes; (void)n_in; (void)out_size;
  const float* x  = (const float*)d_in[0];
  const float* Wf = (const float*)d_in[1];
  const float* bf = (const float*)d_in[2];
  const float* Wg = (const float*)d_in[3];
  const float* bg = (const float*)d_in[4];
  const float* Wh = (const float*)d_in[5];
  const float* bh = (const float*)d_in[6];
  float* out = (float*)d_out;

  // workspace carve-out
  unsigned short* Fw = (unsigned short*)d_ws;
  unsigned short* Gw = Fw + (size_t)BATCH * NPIX * DQK;              // +1MB
  unsigned short* Hw = Gw + (size_t)BATCH * NPIX * DQK;              // +1MB
  unsigned short* Wb = Hw + (size_t)BATCH * CIN * NPIX;              // +8MB
  float* bcat = (float*)(Wb + (size_t)MTOT * CIN);                   // +160KB
  unsigned short* Apart = (unsigned short*)(bcat + MTOT);            // +1.25KB
  float* Lpart = (float*)(Apart + (size_t)2 * BATCH * CIN * NPIX);   // +16MB
  float* Linv  = Lpart + (size_t)8 * BATCH * NPIX;                   // +512KB
  const size_t NEED = (size_t)((char*)(Linv + (size_t)BATCH * NPIX) - (char*)d_ws);  // ~27MB

  hipLaunchKernelGGL(wcvt, dim3(MTOT), dim3(256), 0, stream, Wh, Wf, Wg, bh, bf, bg, Wb, bcat);
  hipLaunchKernelGGL(proj_all, dim3(BATCH * 64), dim3(512), 0, stream, x, Wb, bcat, Fw, Gw, Hw);

  if (ws_size >= NEED) {
    hipLaunchKernelGGL(attn_split, dim3(BATCH * 32 * 2), dim3(512), 0, stream, Fw, Gw, Hw, Apart, Lpart);
    hipLaunchKernelGGL(combineL, dim3(BATCH * NPIX / 256), dim3(256), 0, stream, Lpart, Linv);
    hipLaunchKernelGGL(combine, dim3((size_t)BATCH * CIN * NPIX / 8 / 256), dim3(256), 0, stream, Apart, Linv, out);
  } else {
    hipLaunchKernelGGL(attn_kernel, dim3(BATCH * 64), dim3(512), 0, stream, Fw, Gw, Hw, out);
  }
}